// Round 4
// baseline (59.450 us; speedup 1.0000x reference)
//
#include <hip/hip_runtime.h>

// out[b,n,:] = tables[template_id[b], atom_role[b,n], :]   (all fp32)
// B=4096, N=128, T=64, R=16, D=128.
//
// Strategy: one block per batch b. template_id[b] is block-uniform, so the
// block needs exactly ONE [R][D] table slice = 8 KB. Stage it + the 128
// roles into LDS once; the steady-state loop is then ds_read_b128 -> NT
// global_store_dwordx4 with no global loads on the critical path —
// structurally identical to the 7.1 TB/s fill kernel.

constexpr int B = 4096;
constexpr int N = 128;
constexpr int R = 16;
constexpr int D = 128;
constexpr int BLOCK = 256;
constexpr int F4_PER_BLOCK = N * D / 4;   // 4096 float4 written per block
constexpr int ITERS = F4_PER_BLOCK / BLOCK;  // 16 per thread

typedef float floatx4 __attribute__((ext_vector_type(4)));

__global__ __launch_bounds__(BLOCK) void role_embed_gather(
    const int* __restrict__ template_id,   // [B]
    const int* __restrict__ atom_role,     // [B*N]
    const float* __restrict__ tables,      // [T*R*D]
    floatx4* __restrict__ out)             // [B*N*D/4]
{
    __shared__ float s_tab[R * D];         // 8 KB: tables[t]
    __shared__ int   s_role[N];            // 512 B: roles for this batch

    const int b   = blockIdx.x;
    const int tid = threadIdx.x;

    // Stage roles (128 ints, one coalesced 512B load).
    if (tid < N) s_role[tid] = atom_role[(b << 7) + tid];

    // Stage tables[t] (8 KB = 512 float4; 2 per thread). t is block-uniform
    // -> s_load + uniform base; loads are L2-resident after first touch.
    const int t = template_id[b];
    const floatx4* src = reinterpret_cast<const floatx4*>(&tables[t * (R * D)]);
    floatx4* dtab = reinterpret_cast<floatx4*>(s_tab);
    dtab[tid]         = src[tid];
    dtab[tid + BLOCK] = src[tid + BLOCK];
    __syncthreads();

    // Thread -> (row, col) mapping: element e = i*256 + tid within the block,
    // row = e>>5 = i*8 + (tid>>5), col = e&31. Global f4 index collapses to
    // b*4096 + i*256 + tid -> perfectly contiguous 64 KB per block.
    const int col  = tid & 31;
    const int row0 = tid >> 5;

    // Pre-lift this thread's 16 roles out of LDS (broadcast reads, free) so
    // the table ds_read doesn't chain on a role ds_read.
    int role_v[ITERS];
#pragma unroll
    for (int i = 0; i < ITERS; ++i)
        role_v[i] = s_role[row0 + i * 8];

    floatx4* outb = out + (size_t)b * F4_PER_BLOCK;
#pragma unroll
    for (int i = 0; i < ITERS; ++i) {
        const floatx4 v = *reinterpret_cast<const floatx4*>(
            &s_tab[role_v[i] * D + (col << 2)]);
        __builtin_nontemporal_store(v, &outb[i * BLOCK + tid]);
    }
}

extern "C" void kernel_launch(void* const* d_in, const int* in_sizes, int n_in,
                              void* d_out, int out_size, void* d_ws, size_t ws_size,
                              hipStream_t stream) {
    const int*   template_id = (const int*)d_in[0];
    const int*   atom_role   = (const int*)d_in[1];
    const float* tables      = (const float*)d_in[2];
    floatx4*     out         = (floatx4*)d_out;

    role_embed_gather<<<B, BLOCK, 0, stream>>>(template_id, atom_role, tables, out);
}

// Round 5
// 46.443 us; speedup vs baseline: 1.2801x; 1.2801x over previous
//
#include <hip/hip_runtime.h>

// out[b,n,:] = tables[template_id[b], atom_role[b,n], :]   (all fp32)
// B=4096, N=128, T=64, R=16, D=128.
// 256 MiB streaming write (dominant) + ~2.5 MB cached reads -> write-BW-bound.
// Model: HBM write-drain backpressure governs; fill kernel drains 7.0 TB/s.
// R5 isolates the nt-store flag (R3 = unroll8 + nt landed at 5.0 TB/s).

constexpr int B = 4096;
constexpr int N = 128;
constexpr int R = 16;
constexpr int D = 128;
constexpr int F4_PER_ROW = D / 4;                 // 32 float4 per output row
constexpr int TOTAL_F4   = B * N * F4_PER_ROW;    // 16,777,216
constexpr int UNROLL     = 8;
constexpr int BLOCK      = 256;
constexpr int GRID       = TOTAL_F4 / (BLOCK * UNROLL);  // 8192, exact

typedef float floatx4 __attribute__((ext_vector_type(4)));

__global__ __launch_bounds__(BLOCK) void role_embed_gather(
    const int* __restrict__ template_id,   // [B]
    const int* __restrict__ atom_role,     // [B*N]
    const float* __restrict__ tables,      // [T*R*D]
    floatx4* __restrict__ out)             // [B*N*D/4]
{
    const int base = blockIdx.x * (BLOCK * UNROLL) + threadIdx.x;

    // Phase 1: all index loads issued back-to-back (independent, L1/L2-hit).
    int t[UNROLL], r[UNROLL];
#pragma unroll
    for (int k = 0; k < UNROLL; ++k) {
        const int e   = base + k * BLOCK;
        const int row = e >> 5;            // (b,n) row;  F4_PER_ROW = 32
        t[k] = template_id[row >> 7];      // N = 128
        r[k] = atom_role[row];
    }

    // Phase 2: 8 independent table loads (512 KB table -> L2-resident).
    floatx4 v[UNROLL];
#pragma unroll
    for (int k = 0; k < UNROLL; ++k) {
        const int e  = base + k * BLOCK;
        const int c4 = e & 31;
        v[k] = *reinterpret_cast<const floatx4*>(
            &tables[(t[k] * R + r[k]) * D + (c4 << 2)]);
    }

    // Phase 3: coalesced PLAIN stores (isolating the nt flag vs R3).
#pragma unroll
    for (int k = 0; k < UNROLL; ++k) {
        const int e = base + k * BLOCK;
        out[e] = v[k];
    }
}

extern "C" void kernel_launch(void* const* d_in, const int* in_sizes, int n_in,
                              void* d_out, int out_size, void* d_ws, size_t ws_size,
                              hipStream_t stream) {
    const int*   template_id = (const int*)d_in[0];
    const int*   atom_role   = (const int*)d_in[1];
    const float* tables      = (const float*)d_in[2];
    floatx4*     out         = (floatx4*)d_out;

    role_embed_gather<<<GRID, BLOCK, 0, stream>>>(template_id, atom_role, tables, out);
}